// Round 9
// baseline (131.122 us; speedup 1.0000x reference)
//
#include <hip/hip_runtime.h>
#include <hip/hip_bf16.h>
#include <math.h>

#define DD 64    // feature dim
#define REPS 16  // DIAGNOSTIC: re-execute whole pipeline; output idempotent.
                 // 16 x 16.8 MB writes == the harness fills' 268 MB, forcing
                 // this dispatch into the rocprof top-5 with full counters.

typedef __bf16 bf16x8 __attribute__((ext_vector_type(8)));
typedef float f32x4 __attribute__((ext_vector_type(4)));

// Convert 8 fp32 -> bf16 fragment, accumulating sum of squares of the
// bf16-ROUNDED values into s (so d^2 = nx+ny-2dot = ||xb-yb||^2 >= 0).
__device__ inline bf16x8 cvt8n(const float4 a, const float4 b, float& s) {
  bf16x8 r;
  float t;
  r[0] = (__bf16)a.x; t = (float)r[0]; s = fmaf(t, t, s);
  r[1] = (__bf16)a.y; t = (float)r[1]; s = fmaf(t, t, s);
  r[2] = (__bf16)a.z; t = (float)r[2]; s = fmaf(t, t, s);
  r[3] = (__bf16)a.w; t = (float)r[3]; s = fmaf(t, t, s);
  r[4] = (__bf16)b.x; t = (float)r[4]; s = fmaf(t, t, s);
  r[5] = (__bf16)b.y; t = (float)r[5]; s = fmaf(t, t, s);
  r[6] = (__bf16)b.z; t = (float)r[6]; s = fmaf(t, t, s);
  r[7] = (__bf16)b.w; t = (float)r[7]; s = fmaf(t, t, s);
  return r;
}

// R7 structure (best, 16.2us) wrapped in a REPS loop for counter visibility.
// no __restrict__ on purpose: with the asm memory clobber the compiler must
// re-issue the loads (and thus the convert/MFMA/store pipeline) every rep.
__global__ __launch_bounds__(256) void cdist_fused(
    const float* x, const float* y, float* out, int N, int M) {
  const int lane = threadIdx.x & 63;
  const int wid  = threadIdx.x >> 6;         // 0..3
  const int wr = wid >> 1, wc = wid & 1;     // 2x2 wave grid
  const int i0 = blockIdx.y * 64 + wr * 32;  // wave's x-row base
  const int j0 = blockIdx.x * 64 + wc * 32;  // wave's y-row base
  const int lrow = lane & 15;
  const int kgrp = lane >> 4;

  for (int it = 0; it < REPS; ++it) {
    bf16x8 a[2][2], b[2][2];
    float sa[2] = {0.f, 0.f}, sb[2] = {0.f, 0.f};
    #pragma unroll
    for (int m = 0; m < 2; ++m) {
      #pragma unroll
      for (int ks = 0; ks < 2; ++ks) {
        const float* px = &x[(size_t)(i0 + m * 16 + lrow) * DD + ks * 32 + kgrp * 8];
        a[m][ks] = cvt8n(*reinterpret_cast<const float4*>(px),
                         *reinterpret_cast<const float4*>(px + 4), sa[m]);
        const float* py = &y[(size_t)(j0 + m * 16 + lrow) * DD + ks * 32 + kgrp * 8];
        b[m][ks] = cvt8n(*reinterpret_cast<const float4*>(py),
                         *reinterpret_cast<const float4*>(py + 4), sb[m]);
      }
    }

    #pragma unroll
    for (int m = 0; m < 2; ++m) {
      sa[m] += __shfl_xor(sa[m], 16, 64);
      sa[m] += __shfl_xor(sa[m], 32, 64);
      sb[m] += __shfl_xor(sb[m], 16, 64);
      sb[m] += __shfl_xor(sb[m], 32, 64);
    }

    f32x4 acc[2][2] = {};  // acc[n][m]
    #pragma unroll
    for (int ks = 0; ks < 2; ++ks)
      #pragma unroll
      for (int n = 0; n < 2; ++n)
        #pragma unroll
        for (int m = 0; m < 2; ++m)
          acc[n][m] = __builtin_amdgcn_mfma_f32_16x16x32_bf16(
              b[n][ks], a[m][ks], acc[n][m], 0, 0, 0);

    #pragma unroll
    for (int n = 0; n < 2; ++n) {
      float nyv[4];
      #pragma unroll
      for (int r = 0; r < 4; ++r) nyv[r] = __shfl(sb[n], kgrp * 4 + r, 64);
      #pragma unroll
      for (int m = 0; m < 2; ++m) {
        f32x4 res;
        float d2;
        d2 = fmaf(-2.0f, acc[n][m][0], sa[m] + nyv[0]); res[0] = sqrtf(fmaxf(d2, 0.f));
        d2 = fmaf(-2.0f, acc[n][m][1], sa[m] + nyv[1]); res[1] = sqrtf(fmaxf(d2, 0.f));
        d2 = fmaf(-2.0f, acc[n][m][2], sa[m] + nyv[2]); res[2] = sqrtf(fmaxf(d2, 0.f));
        d2 = fmaf(-2.0f, acc[n][m][3], sa[m] + nyv[3]); res[3] = sqrtf(fmaxf(d2, 0.f));
        __builtin_nontemporal_store(
            res, reinterpret_cast<f32x4*>(
                &out[(size_t)(i0 + m * 16 + lrow) * M + j0 + n * 16 + kgrp * 4]));
      }
    }
    asm volatile("" ::: "memory");  // force full re-execution each rep
  }
}

extern "C" void kernel_launch(void* const* d_in, const int* in_sizes, int n_in,
                              void* d_out, int out_size, void* d_ws, size_t ws_size,
                              hipStream_t stream) {
  const float* x = (const float*)d_in[0];
  const float* y = (const float*)d_in[1];
  float* out = (float*)d_out;
  const int N = in_sizes[0] / DD;  // 2048
  const int M = in_sizes[1] / DD;  // 2048

  cdist_fused<<<dim3(M / 64, N / 64), dim3(256), 0, stream>>>(x, y, out, N, M);
}

// Round 10
// 18.274 us; speedup vs baseline: 7.1755x; 7.1755x over previous
//
#include <hip/hip_runtime.h>
#include <hip/hip_bf16.h>
#include <math.h>

#define DD 64  // feature dim

typedef __bf16 bf16x8 __attribute__((ext_vector_type(8)));
typedef float f32x4 __attribute__((ext_vector_type(4)));

// Kernel A: fp32 -> bf16 conversion + row norms of the bf16-ROUNDED values
// (so d^2 = nx+ny-2*dot = ||xb-yb||^2 >= 0 up to MFMA rounding).
// One wave per row, one element per lane. Runs once; O(N*D) work.
__global__ __launch_bounds__(256) void convert_norm(
    const float* __restrict__ x, const float* __restrict__ y,
    __hip_bfloat16* __restrict__ xb, __hip_bfloat16* __restrict__ yb,
    float* __restrict__ nx, float* __restrict__ ny, int N, int M) {
  const int w = (blockIdx.x * blockDim.x + threadIdx.x) >> 6;
  const int lane = threadIdx.x & 63;

  const float* src;
  __hip_bfloat16* dst;
  float* nrm;
  int r;
  if (w < N) {
    src = x; dst = xb; nrm = nx; r = w;
  } else {
    r = w - N;
    if (r >= M) return;
    src = y; dst = yb; nrm = ny;
  }

  const float v = src[r * DD + lane];
  const __hip_bfloat16 b = __float2bfloat16(v);
  dst[r * DD + lane] = b;
  const float f = __bfloat162float(b);
  float s = f * f;
  #pragma unroll
  for (int off = 32; off > 0; off >>= 1) s += __shfl_down(s, off, 64);
  if (lane == 0) nrm[r] = s;
}

// Kernel B: out[i][j] = sqrt(max(nx[i] + ny[j] - 2 * xb_i.yb_j, 0)).
// Block = 4 independent waves (2x2), each wave a 32x32 tile. Fragments load
// as single dwordx4 from the precomputed bf16 arrays (NO convert, NO norm
// VALU work, NO shuffles -- R9 diagnostic showed the fused kernel was
// VALU/shuffle-latency bound at 44% VALUBusy from 64x-redundant conversion).
// Swapped-operand MFMA (y as A, x as B): C/D row->j, col->i, so each lane's
// 4 acc regs are 4 consecutive j -> one nontemporal float4 store per frag.
__global__ __launch_bounds__(256) void cdist_main(
    const __hip_bfloat16* __restrict__ xb, const __hip_bfloat16* __restrict__ yb,
    const float* __restrict__ nx, const float* __restrict__ ny,
    float* __restrict__ out, int M) {
  const int lane = threadIdx.x & 63;
  const int wid  = threadIdx.x >> 6;         // 0..3
  const int wr = wid >> 1, wc = wid & 1;     // 2x2 wave grid
  const int i0 = blockIdx.y * 64 + wr * 32;  // wave's x-row base
  const int j0 = blockIdx.x * 64 + wc * 32;  // wave's y-row base
  const int lrow = lane & 15;
  const int kgrp = lane >> 4;

  // A/B layout: lane l holds 8 contiguous k-elems of row (l&15) at k-offset
  // (l>>4)*8 (+32 per k-step). One 16B load per fragment.
  bf16x8 a[2][2], b[2][2];
  #pragma unroll
  for (int m = 0; m < 2; ++m) {
    #pragma unroll
    for (int ks = 0; ks < 2; ++ks) {
      a[m][ks] = *reinterpret_cast<const bf16x8*>(
          &xb[(size_t)(i0 + m * 16 + lrow) * DD + ks * 32 + kgrp * 8]);
      b[m][ks] = *reinterpret_cast<const bf16x8*>(
          &yb[(size_t)(j0 + m * 16 + lrow) * DD + ks * 32 + kgrp * 8]);
    }
  }

  // Norms via direct (cached/broadcast) loads -- no cross-lane ops.
  const float nxa[2] = {nx[i0 + lrow], nx[i0 + 16 + lrow]};
  float4 nyv[2];
  #pragma unroll
  for (int n = 0; n < 2; ++n)
    nyv[n] = *reinterpret_cast<const float4*>(&ny[j0 + n * 16 + kgrp * 4]);

  // Swapped-operand MFMA: D[row -> j][col -> i].
  f32x4 acc[2][2] = {};  // acc[n][m]
  #pragma unroll
  for (int ks = 0; ks < 2; ++ks)
    #pragma unroll
    for (int n = 0; n < 2; ++n)
      #pragma unroll
      for (int m = 0; m < 2; ++m)
        acc[n][m] = __builtin_amdgcn_mfma_f32_16x16x32_bf16(
            b[n][ks], a[m][ks], acc[n][m], 0, 0, 0);

  // Epilogue: element (m, n, reg r): i = i0 + m*16 + lrow, j = j0 + n*16 +
  // kgrp*4 + r. x-norm = nxa[m]; y-norms = nyv[n] components.
  #pragma unroll
  for (int n = 0; n < 2; ++n) {
    #pragma unroll
    for (int m = 0; m < 2; ++m) {
      f32x4 res;
      float d2;
      d2 = fmaf(-2.0f, acc[n][m][0], nxa[m] + nyv[n].x); res[0] = sqrtf(fmaxf(d2, 0.f));
      d2 = fmaf(-2.0f, acc[n][m][1], nxa[m] + nyv[n].y); res[1] = sqrtf(fmaxf(d2, 0.f));
      d2 = fmaf(-2.0f, acc[n][m][2], nxa[m] + nyv[n].z); res[2] = sqrtf(fmaxf(d2, 0.f));
      d2 = fmaf(-2.0f, acc[n][m][3], nxa[m] + nyv[n].w); res[3] = sqrtf(fmaxf(d2, 0.f));
      __builtin_nontemporal_store(
          res, reinterpret_cast<f32x4*>(
              &out[(size_t)(i0 + m * 16 + lrow) * M + j0 + n * 16 + kgrp * 4]));
    }
  }
}

extern "C" void kernel_launch(void* const* d_in, const int* in_sizes, int n_in,
                              void* d_out, int out_size, void* d_ws, size_t ws_size,
                              hipStream_t stream) {
  const float* x = (const float*)d_in[0];
  const float* y = (const float*)d_in[1];
  float* out = (float*)d_out;
  const int N = in_sizes[0] / DD;  // 2048
  const int M = in_sizes[1] / DD;  // 2048

  // Workspace layout (16B-aligned slices).
  char* ws = (char*)d_ws;
  __hip_bfloat16* xb = (__hip_bfloat16*)ws;                        // N*DD*2 B
  __hip_bfloat16* yb = (__hip_bfloat16*)(ws + (size_t)N * DD * 2); // M*DD*2 B
  float* nx = (float*)(ws + (size_t)(N + M) * DD * 2);             // N*4 B
  float* ny = (float*)(ws + (size_t)(N + M) * DD * 2 + (size_t)N * 4);

  const int total_waves = N + M;
  convert_norm<<<dim3((total_waves + 3) / 4), dim3(256), 0, stream>>>(
      x, y, xb, yb, nx, ny, N, M);

  cdist_main<<<dim3(M / 64, N / 64), dim3(256), 0, stream>>>(
      xb, yb, nx, ny, out, M);
}

// Round 11
// 15.065 us; speedup vs baseline: 8.7037x; 1.2130x over previous
//
#include <hip/hip_runtime.h>
#include <hip/hip_bf16.h>
#include <math.h>

#define DD 64  // feature dim

typedef __bf16 bf16x8 __attribute__((ext_vector_type(8)));
typedef float f32x4 __attribute__((ext_vector_type(4)));

// Convert 8 fp32 -> bf16 fragment, accumulating sum of squares of the
// bf16-ROUNDED values into s (so d^2 = nx+ny-2dot = ||xb-yb||^2 >= 0).
__device__ inline bf16x8 cvt8n(const float4 a, const float4 b, float& s) {
  bf16x8 r;
  float t;
  r[0] = (__bf16)a.x; t = (float)r[0]; s = fmaf(t, t, s);
  r[1] = (__bf16)a.y; t = (float)r[1]; s = fmaf(t, t, s);
  r[2] = (__bf16)a.z; t = (float)r[2]; s = fmaf(t, t, s);
  r[3] = (__bf16)a.w; t = (float)r[3]; s = fmaf(t, t, s);
  r[4] = (__bf16)b.x; t = (float)r[4]; s = fmaf(t, t, s);
  r[5] = (__bf16)b.y; t = (float)r[5]; s = fmaf(t, t, s);
  r[6] = (__bf16)b.z; t = (float)r[6]; s = fmaf(t, t, s);
  r[7] = (__bf16)b.w; t = (float)r[7]; s = fmaf(t, t, s);
  return r;
}

// Fused CDist (R7 base + shorter critical path):
//   out[i][j] = sqrt(max(||xb_i||^2 + ||yb_j||^2 - 2 xb_i.yb_j, 0))
// One 32x32 tile per wave, 4 waves/block, 1024 blocks, XCD-swizzled.
// Epilogue y-norm exchange via wave-private LDS (2 ds_write + 4 ds_read_b128)
// instead of 16 serial ds_bpermute (R9 showed a latency-bound single phase).
// Swapped-operand MFMA (y as A, x as B): C/D row->j, col->i -> each lane's
// 4 acc regs are 4 consecutive j -> one nontemporal float4 store per frag.
__global__ __launch_bounds__(256) void cdist_fused(
    const float* __restrict__ x, const float* __restrict__ y,
    float* __restrict__ out, int N, int M) {
  // Bijective XCD swizzle: 1024 blocks, 8 XCDs -> 128 consecutive per XCD.
  const int bid = blockIdx.x;
  const int swz = (bid & 7) * 128 + (bid >> 3);
  const int bx = swz & 31;   // j-tile
  const int by = swz >> 5;   // i-tile

  const int lane = threadIdx.x & 63;
  const int wid  = threadIdx.x >> 6;      // 0..3
  const int wr = wid >> 1, wc = wid & 1;  // 2x2 wave grid
  const int i0 = by * 64 + wr * 32;       // wave's x-row base
  const int j0 = bx * 64 + wc * 32;       // wave's y-row base
  const int lrow = lane & 15;
  const int kgrp = lane >> 4;

  __shared__ float sny[4][32];  // per-wave y-norms [wid][n*16 + lrow]

  // Fragment loads (fp32 global -> bf16 regs) + partial norms.
  // A/B layout: lane l holds 8 contiguous k-elems of row (l&15) at k-offset
  // (l>>4)*8 (+32 per k-step). Verified rounds 2-10.
  bf16x8 a[2][2], b[2][2];
  float sa[2] = {0.f, 0.f}, sb[2] = {0.f, 0.f};
  #pragma unroll
  for (int m = 0; m < 2; ++m) {
    #pragma unroll
    for (int ks = 0; ks < 2; ++ks) {
      const float* px = &x[(size_t)(i0 + m * 16 + lrow) * DD + ks * 32 + kgrp * 8];
      a[m][ks] = cvt8n(*reinterpret_cast<const float4*>(px),
                       *reinterpret_cast<const float4*>(px + 4), sa[m]);
      const float* py = &y[(size_t)(j0 + m * 16 + lrow) * DD + ks * 32 + kgrp * 8];
      b[m][ks] = cvt8n(*reinterpret_cast<const float4*>(py),
                       *reinterpret_cast<const float4*>(py + 4), sb[m]);
    }
  }

  // Butterfly over kgrp bits: full norm of row (base + n*16 + lrow) per lane.
  #pragma unroll
  for (int m = 0; m < 2; ++m) {
    sa[m] += __shfl_xor(sa[m], 16, 64);
    sa[m] += __shfl_xor(sa[m], 32, 64);
    sb[m] += __shfl_xor(sb[m], 16, 64);
    sb[m] += __shfl_xor(sb[m], 32, 64);
  }

  // Publish y-norms to wave-private LDS (kgrp==0 lanes hold lrow=lane).
  if (kgrp == 0) {
    sny[wid][lrow]      = sb[0];
    sny[wid][16 + lrow] = sb[1];
  }

  // Swapped-operand MFMA: D[row -> j][col -> i].
  f32x4 acc[2][2] = {};  // acc[n][m]
  #pragma unroll
  for (int ks = 0; ks < 2; ++ks)
    #pragma unroll
    for (int n = 0; n < 2; ++n)
      #pragma unroll
      for (int m = 0; m < 2; ++m)
        acc[n][m] = __builtin_amdgcn_mfma_f32_16x16x32_bf16(
            b[n][ks], a[m][ks], acc[n][m], 0, 0, 0);

  // Epilogue: element (m, n, reg r): i = i0 + m*16 + lrow (x-norm = own
  // sa[m]); j = j0 + n*16 + kgrp*4 + r (y-norms: one float4 LDS read).
  #pragma unroll
  for (int n = 0; n < 2; ++n) {
    const float4 nyv = *reinterpret_cast<const float4*>(&sny[wid][n * 16 + kgrp * 4]);
    #pragma unroll
    for (int m = 0; m < 2; ++m) {
      f32x4 res;
      float d2;
      d2 = fmaf(-2.0f, acc[n][m][0], sa[m] + nyv.x);
      res[0] = __builtin_amdgcn_sqrtf(fmaxf(d2, 0.f));
      d2 = fmaf(-2.0f, acc[n][m][1], sa[m] + nyv.y);
      res[1] = __builtin_amdgcn_sqrtf(fmaxf(d2, 0.f));
      d2 = fmaf(-2.0f, acc[n][m][2], sa[m] + nyv.z);
      res[2] = __builtin_amdgcn_sqrtf(fmaxf(d2, 0.f));
      d2 = fmaf(-2.0f, acc[n][m][3], sa[m] + nyv.w);
      res[3] = __builtin_amdgcn_sqrtf(fmaxf(d2, 0.f));
      __builtin_nontemporal_store(
          res, reinterpret_cast<f32x4*>(
              &out[(size_t)(i0 + m * 16 + lrow) * M + j0 + n * 16 + kgrp * 4]));
    }
  }
}

extern "C" void kernel_launch(void* const* d_in, const int* in_sizes, int n_in,
                              void* d_out, int out_size, void* d_ws, size_t ws_size,
                              hipStream_t stream) {
  const float* x = (const float*)d_in[0];
  const float* y = (const float*)d_in[1];
  float* out = (float*)d_out;
  const int N = in_sizes[0] / DD;  // 2048
  const int M = in_sizes[1] / DD;  // 2048

  const int nblocks = (N / 64) * (M / 64);  // 1024
  cdist_fused<<<dim3(nblocks), dim3(256), 0, stream>>>(x, y, out, N, M);
}